// Round 8
// baseline (418.945 us; speedup 1.0000x reference)
//
#include <hip/hip_runtime.h>

#define F      8192
#define KD     64     // coordinate dimensionality
#define NB     8      // neighbors
#define WROWS  32     // rows per block (all 8 waves share these rows)
#define MKEEP  16     // per-(row,quarter) approx list length (superset of top-8)
#define JQ     4      // column quarters
#define CPR    128    // cols per block-round (8 waves x 16)
#define NROUND ((F / JQ) / CPR)   // 16
#define CAP    160    // round 0 uses 128 fixed slots; later intervals use appends
#define MARGIN 0.25f  // >> 2x max |d_approx - d_exact| (~0.04)

typedef unsigned long long u64;
typedef unsigned short ushort_t;
typedef __attribute__((ext_vector_type(8))) short bf16x8;  // 8 bf16 = 4 VGPRs
typedef __attribute__((ext_vector_type(4))) float f32x4;

__device__ __forceinline__ u64 pack64(float d, int j) {
    // d >= 0 -> f32 bits order-preserving; u64 ascending == lex (d, j)
    return ((u64)__float_as_uint(d) << 32) | (unsigned)j;
}

__device__ __forceinline__ unsigned bf16rn(float x) {
    unsigned u = __float_as_uint(x);
    return (u + 0x7fffu + ((u >> 16) & 1u)) >> 16;
}

// ---------------------------------------------------------------------------
// Kernel 1: prep. sq (exact ascending-k fmaf chain — recheck uses the same
// chain so dot(i,i)==sq[i] bit-exact => d(i,i)==0), transposed bf16 hi/lo
// split (MFMA fragments = contiguous 16B), and transposed fp32 Xt32 (recheck
// reads contiguous 256B rows).
// ---------------------------------------------------------------------------
__global__ __launch_bounds__(256) void prep_kernel(const float* __restrict__ crd,
                                                   float* __restrict__ sq,
                                                   ushort_t* __restrict__ XtHi,
                                                   ushort_t* __restrict__ XtLo,
                                                   float* __restrict__ Xt32) {
    const int f = blockIdx.x * 256 + threadIdx.x;
    float acc = 0.f;
#pragma unroll
    for (int kb = 0; kb < 8; ++kb) {
        ushort_t hb[8], lb[8];
        float    xv[8];
#pragma unroll
        for (int u = 0; u < 8; ++u) {
            int k = kb * 8 + u;
            float x = crd[k * F + f];
            acc = fmaf(x, x, acc);
            unsigned h = bf16rn(x);
            float hf = __uint_as_float(h << 16);
            unsigned l = bf16rn(x - hf);       // Dekker split, exact residual
            hb[u] = (ushort_t)h; lb[u] = (ushort_t)l; xv[u] = x;
        }
        *(uint4*)&XtHi[(size_t)f * KD + kb * 8] = *(const uint4*)hb;
        *(uint4*)&XtLo[(size_t)f * KD + kb * 8] = *(const uint4*)lb;
        *(float4*)&Xt32[(size_t)f * KD + kb * 8]     = *(const float4*)&xv[0];
        *(float4*)&Xt32[(size_t)f * KD + kb * 8 + 4] = *(const float4*)&xv[4];
    }
    sq[f] = acc;
}

// ---------------------------------------------------------------------------
// Kernel 2: MFMA distance + approx top-16 per (row, col-quarter).
// R7 post-mortem fixes: (1) __launch_bounds__(512,2) — R7's (512,4) forced
// VGPR=64 and spilled the ~100-reg hot state to scratch (MfmaUtil 3.7%,
// both pipes idle); (2) round 0 writes to fixed slots buf[row][wave*16+n]
// (no 4096 same-address atomics); (3) lst padded +1 — 128B row stride put
// all 32 fold lanes on one bank (the 3.9e6 conflicts).
// Structure: 8 waves share 32 rows (A frags in regs), distinct 16-col
// stripes; 12 MFMAs / 4KB B; unroll-2 double-buffered B prefetch; accept
// test dot >= pre[r] + 0.5*sqj; folds at rounds 0,1,3,7,15.
// ---------------------------------------------------------------------------
__global__ __launch_bounds__(512, 2) void knn_mfma(const ushort_t* __restrict__ XtHi,
                                                   const ushort_t* __restrict__ XtLo,
                                                   const float* __restrict__ sq,
                                                   u64* __restrict__ part) {
    __shared__ u64 buf[WROWS][CAP + 1];     // 41.2 KB
    __shared__ u64 lst[WROWS][MKEEP + 1];   // 4.35 KB (pad: fold 2-way banks)
    __shared__ __align__(16) float thr[WROWS];
    __shared__ int cnt[WROWS];

    const int tid  = threadIdx.x;
    const int wave = tid >> 6;
    const int tx   = tid & 63;
    const int quad = tx >> 4;
    const int n    = tx & 15;
    const int blockRow = (blockIdx.x >> 2) * WROWS;
    const int jq    = blockIdx.x & 3;
    const int jbase = jq * (F / JQ);

    if (tid < WROWS) { cnt[tid] = 0; thr[tid] = __int_as_float(0x7f800000); }
#pragma unroll
    for (int e = tid; e < WROWS * MKEEP; e += 512) lst[e >> 4][e & 15] = ~0ULL;
    __syncthreads();

    // A fragments for both 16-row tiles, resident all sweep (32 VGPRs)
    const size_t a0 = (size_t)(blockRow + n) * KD + quad * 8;
    const size_t a1 = (size_t)(blockRow + 16 + n) * KD + quad * 8;
    const bf16x8 a0h0 = *(const bf16x8*)(XtHi + a0), a0h1 = *(const bf16x8*)(XtHi + a0 + 32);
    const bf16x8 a0l0 = *(const bf16x8*)(XtLo + a0), a0l1 = *(const bf16x8*)(XtLo + a0 + 32);
    const bf16x8 a1h0 = *(const bf16x8*)(XtHi + a1), a1h1 = *(const bf16x8*)(XtHi + a1 + 32);
    const bf16x8 a1l0 = *(const bf16x8*)(XtLo + a1), a1l1 = *(const bf16x8*)(XtLo + a1 + 32);
    const f32x4 sqi0 = *(const f32x4*)&sq[blockRow + quad * 4];
    const f32x4 sqi1 = *(const f32x4*)&sq[blockRow + 16 + quad * 4];
    f32x4 pre0, pre1;   // 0.5*(sqi - thr)
#pragma unroll
    for (int r = 0; r < 4; ++r) { pre0[r] = -__int_as_float(0x7f800000);
                                  pre1[r] = -__int_as_float(0x7f800000); }

    const int laneCol = wave * 16 + n;    // col offset within a round's 128

#define LOADB(H0, H1, L0, L1, SJ, RND)                                        \
    {   int jc = jbase + (RND) * CPR + laneCol;                               \
        size_t bo = (size_t)jc * KD + quad * 8;                               \
        H0 = *(const bf16x8*)(XtHi + bo); H1 = *(const bf16x8*)(XtHi + bo + 32); \
        L0 = *(const bf16x8*)(XtLo + bo); L1 = *(const bf16x8*)(XtLo + bo + 32); \
        SJ = sq[jc]; }

#define MFMABODY(H0, H1, L0, L1)                                              \
        f32x4 za0 = {0,0,0,0}, zb0 = {0,0,0,0}, za1 = {0,0,0,0}, zb1 = {0,0,0,0}; \
        za0 = __builtin_amdgcn_mfma_f32_16x16x32_bf16(a0h0, H0, za0, 0, 0, 0); \
        za0 = __builtin_amdgcn_mfma_f32_16x16x32_bf16(a0h1, H1, za0, 0, 0, 0); \
        zb0 = __builtin_amdgcn_mfma_f32_16x16x32_bf16(a0h0, L0, zb0, 0, 0, 0); \
        zb0 = __builtin_amdgcn_mfma_f32_16x16x32_bf16(a0h1, L1, zb0, 0, 0, 0); \
        zb0 = __builtin_amdgcn_mfma_f32_16x16x32_bf16(a0l0, H0, zb0, 0, 0, 0); \
        zb0 = __builtin_amdgcn_mfma_f32_16x16x32_bf16(a0l1, H1, zb0, 0, 0, 0); \
        za1 = __builtin_amdgcn_mfma_f32_16x16x32_bf16(a1h0, H0, za1, 0, 0, 0); \
        za1 = __builtin_amdgcn_mfma_f32_16x16x32_bf16(a1h1, H1, za1, 0, 0, 0); \
        zb1 = __builtin_amdgcn_mfma_f32_16x16x32_bf16(a1h0, L0, zb1, 0, 0, 0); \
        zb1 = __builtin_amdgcn_mfma_f32_16x16x32_bf16(a1h1, L1, zb1, 0, 0, 0); \
        zb1 = __builtin_amdgcn_mfma_f32_16x16x32_bf16(a1l0, H0, zb1, 0, 0, 0); \
        zb1 = __builtin_amdgcn_mfma_f32_16x16x32_bf16(a1l1, H1, zb1, 0, 0, 0);

// round 0: accept-all, deterministic slot = laneCol (no atomics)
#define PROCESS0(H0, H1, L0, L1, SJ, RND)                                     \
    {   MFMABODY(H0, H1, L0, L1)                                              \
        const int jc = jbase + (RND) * CPR + laneCol;                         \
        _Pragma("unroll")                                                     \
        for (int r = 0; r < 4; ++r) {                                         \
            float d0 = fmaxf((sqi0[r] + SJ) - 2.f * (za0[r] + zb0[r]), 0.f);  \
            buf[quad * 4 + r][laneCol] = pack64(d0, jc);                      \
            float d1 = fmaxf((sqi1[r] + SJ) - 2.f * (za1[r] + zb1[r]), 0.f);  \
            buf[16 + quad * 4 + r][laneCol] = pack64(d1, jc);                 \
        } }

#define PROCESS(H0, H1, L0, L1, SJ, RND)                                      \
    {   MFMABODY(H0, H1, L0, L1)                                              \
        const int jc = jbase + (RND) * CPR + laneCol;                         \
        const float h = 0.5f * SJ;                                            \
        _Pragma("unroll")                                                     \
        for (int r = 0; r < 4; ++r) {                                         \
            float dot = za0[r] + zb0[r];                                      \
            if (dot >= pre0[r] + h) {                                         \
                float d = fmaxf((sqi0[r] + SJ) - 2.f * dot, 0.f);             \
                int row = quad * 4 + r;                                       \
                int q = atomicAdd(&cnt[row], 1);                              \
                if (q < CAP) buf[row][q] = pack64(d, jc);                     \
            }                                                                 \
            dot = za1[r] + zb1[r];                                            \
            if (dot >= pre1[r] + h) {                                         \
                float d = fmaxf((sqi1[r] + SJ) - 2.f * dot, 0.f);             \
                int row = 16 + quad * 4 + r;                                  \
                int q = atomicAdd(&cnt[row], 1);                              \
                if (q < CAP) buf[row][q] = pack64(d, jc);                     \
            }                                                                 \
        } }

#define FOLD(NN)                                                              \
    {   __syncthreads();                                                      \
        if (tid < WROWS) {                                                    \
            u64 L[MKEEP];                                                     \
            _Pragma("unroll")                                                 \
            for (int s = 0; s < MKEEP; ++s) L[s] = lst[tid][s];               \
            int nn = min((NN), CAP);                                          \
            for (int ii = 0; ii < nn; ++ii) {                                 \
                u64 x = buf[tid][ii];                                         \
                if (x < L[MKEEP - 1]) {                                       \
                    L[MKEEP - 1] = x;                                         \
                    _Pragma("unroll")                                         \
                    for (int q = MKEEP - 1; q > 0; --q)                       \
                        if (L[q] < L[q - 1]) { u64 w = L[q]; L[q] = L[q - 1]; L[q - 1] = w; } \
                }                                                             \
            }                                                                 \
            _Pragma("unroll")                                                 \
            for (int s = 0; s < MKEEP; ++s) lst[tid][s] = L[s];               \
            thr[tid] = __uint_as_float((unsigned)(L[NB - 1] >> 32)) + MARGIN; \
            cnt[tid] = 0;                                                     \
        }                                                                     \
        __syncthreads();                                                      \
        {   f32x4 t0 = *(const f32x4*)&thr[quad * 4];                         \
            f32x4 t1 = *(const f32x4*)&thr[16 + quad * 4];                    \
            _Pragma("unroll")                                                 \
            for (int r = 0; r < 4; ++r) {                                     \
                pre0[r] = 0.5f * (sqi0[r] - t0[r]);                           \
                pre1[r] = 0.5f * (sqi1[r] - t1[r]);                           \
            } } }

    bf16x8 B0h0, B0h1, B0l0, B0l1, B1h0, B1h1, B1l0, B1l1;
    float  B0sj, B1sj;
    LOADB(B0h0, B0h1, B0l0, B0l1, B0sj, 0)
    LOADB(B1h0, B1h1, B1l0, B1l1, B1sj, 1)

    // round 0 (accept-all, fixed slots) + fold(128)
    PROCESS0(B0h0, B0h1, B0l0, B0l1, B0sj, 0)
    LOADB(B0h0, B0h1, B0l0, B0l1, B0sj, 2)
    FOLD(128)
    PROCESS(B1h0, B1h1, B1l0, B1l1, B1sj, 1)
    LOADB(B1h0, B1h1, B1l0, B1l1, B1sj, 3)
    FOLD(cnt[tid])

    for (int rr = 2; rr < NROUND; rr += 2) {
        PROCESS(B0h0, B0h1, B0l0, B0l1, B0sj, rr)
        if (rr + 2 < NROUND) LOADB(B0h0, B0h1, B0l0, B0l1, B0sj, rr + 2)
        PROCESS(B1h0, B1h1, B1l0, B1l1, B1sj, rr + 1)
        if (rr + 3 < NROUND) LOADB(B1h0, B1h1, B1l0, B1l1, B1sj, rr + 3)
        if (((rr + 1) & (rr + 2)) == 0) FOLD(cnt[tid])   // rounds 3,7,15
    }

    // write per-quarter top-16 lists (final fold happened at round 15)
#pragma unroll
    for (int e = tid; e < WROWS * MKEEP; e += 512) {
        int rrw = e >> 4, ss = e & 15;
        part[((size_t)jq * F + blockRow + rrw) * MKEEP + ss] = lst[rrw][ss];
    }
#undef LOADB
#undef MFMABODY
#undef PROCESS0
#undef PROCESS
#undef FOLD
}

// ---------------------------------------------------------------------------
// Kernel 3: exact recheck. Block = 4 rows x 64 candidates (one row per wave).
// B rows contiguous from Xt32 (256B/candidate, L2-hot); A row in LDS.
// Exact ascending-k fmaf chain (bit-identical to sq's => d(i,i)==0).
// Top-8 via in-register wave shuffle-pop on packed u64 -> exact jax tie-break.
// ---------------------------------------------------------------------------
__global__ __launch_bounds__(256) void recheck_kernel(const float* __restrict__ Xt32,
                                                      const float* __restrict__ sq,
                                                      const u64* __restrict__ part,
                                                      int* __restrict__ knn) {
    __shared__ float A_s[4][KD];
    const int tid = threadIdx.x;
    const int rl = tid >> 6, tx = tid & 63;
    const int i = blockIdx.x * 4 + rl;

    A_s[tid >> 6][tid & 63] = Xt32[(size_t)(blockIdx.x * 4 + (tid >> 6)) * KD + (tid & 63)];
    __syncthreads();

    u64 pc = part[((size_t)(tx >> 4) * F + i) * MKEEP + (tx & 15)];
    int j = (int)(pc & 0xffffffffu);

    const float4* b4 = (const float4*)(Xt32 + (size_t)j * KD);
    float acc = 0.f;
#pragma unroll
    for (int kk = 0; kk < KD / 4; ++kk) {
        float4 b = b4[kk];
        const float* a = &A_s[rl][kk * 4];
        acc = fmaf(a[0], b.x, acc);
        acc = fmaf(a[1], b.y, acc);
        acc = fmaf(a[2], b.z, acc);
        acc = fmaf(a[3], b.w, acc);
    }
    float d = fmaxf((sq[i] + sq[j]) - 2.f * acc, 0.f);
    u64 mine = pack64(d, j);

    int myout = 0;
#pragma unroll
    for (int s = 0; s < NB; ++s) {
        u64 m = mine;
#pragma unroll
        for (int off = 32; off >= 1; off >>= 1) {
            u64 o = __shfl_xor(m, off, 64);
            if (o < m) m = o;
        }
        if (mine == m) mine = ~0ULL;       // pop (unique (d,j) per row)
        if (tx == s) myout = (int)(m & 0xffffffffu);
    }
    if (tx < NB) knn[(size_t)i * NB + tx] = myout;
}

// ---------------------------------------------------------------------------
// Kernel 4: gather. 4 blocks per (b,c); row staged in LDS; int4 knn +
// float4 stores, coalesced.
// ---------------------------------------------------------------------------
__global__ __launch_bounds__(512) void gather_kernel(const float* __restrict__ inp,
                                                     const int* __restrict__ knn,
                                                     float* __restrict__ out) {
    __shared__ float row[F];    // 32 KB
    const int bc    = blockIdx.x >> 2;
    const int chunk = blockIdx.x & 3;
    const int tid   = threadIdx.x;

    const float4* in4  = (const float4*)(inp + (size_t)bc * F);
    float4*       row4 = (float4*)row;
#pragma unroll
    for (int i = 0; i < (F / 4) / 512; ++i) row4[i * 512 + tid] = in4[i * 512 + tid];
    __syncthreads();

    const int4* kn4 = (const int4*)knn;
    float4*     ou4 = (float4*)(out + (size_t)bc * (F * NB));

#pragma unroll
    for (int i = 0; i < 8; ++i) {
        int e = chunk * 4096 + i * 512 + tid;
        int4 idx = kn4[e];
        if (e == 0) idx.x = 0;             // flat_idx[0] hardcoded 0
        float4 o;
        o.x = row[idx.x]; o.y = row[idx.y]; o.z = row[idx.z]; o.w = row[idx.w];
        ou4[e] = o;
    }
}

extern "C" void kernel_launch(void* const* d_in, const int* in_sizes, int n_in,
                              void* d_out, int out_size, void* d_ws, size_t ws_size,
                              hipStream_t stream) {
    const float* inp = (const float*)d_in[0];   // (64,4,8192,1) fp32
    const float* crd = (const float*)d_in[1];   // (64,1,8192)  fp32
    float* out = (float*)d_out;                 // (64,4,65536,1) fp32

    ushort_t* XtHi = (ushort_t*)d_ws;                               // 1 MB
    ushort_t* XtLo = (ushort_t*)((char*)d_ws + (1u << 20));         // 1 MB
    float*    Xt32 = (float*)((char*)d_ws + (2u << 20));            // 2 MB
    float*    sq   = (float*)((char*)d_ws + (4u << 20));            // 32 KB
    int*      knn  = (int*)((char*)d_ws + (4u << 20) + (1u << 15)); // 256 KB
    u64*      part = (u64*)((char*)d_ws + (5u << 20));              // 4 MB

    prep_kernel<<<F / 256, 256, 0, stream>>>(crd, sq, XtHi, XtLo, Xt32);
    knn_mfma<<<(F / WROWS) * JQ, 512, 0, stream>>>(XtHi, XtLo, sq, part);
    recheck_kernel<<<F / 4, 256, 0, stream>>>(Xt32, sq, part, knn);
    gather_kernel<<<256 * 4, 512, 0, stream>>>(inp, knn, out);
}

// Round 9
// 267.581 us; speedup vs baseline: 1.5657x; 1.5657x over previous
//
#include <hip/hip_runtime.h>

#define F      8192
#define KD     64     // coordinate dimensionality
#define NB     8      // neighbors
#define WROWS  32     // rows per block (all 4 waves share these rows)
#define MKEEP  16     // per-(row,quarter) approx list length (superset of top-8)
#define JQ     4      // column quarters
#define CPR    64     // cols per block-round (4 waves x 16)
#define NROUND ((F / JQ) / CPR)   // 32
#define CAP    96     // per-row candidate buffer capacity per fold interval
#define MARGIN 0.25f  // >> 2x max |d_approx - d_exact| (~0.04)

typedef unsigned long long u64;
typedef unsigned short ushort_t;
typedef __attribute__((ext_vector_type(8))) short bf16x8;  // 8 bf16 = 4 VGPRs
typedef __attribute__((ext_vector_type(4))) float f32x4;

__device__ __forceinline__ u64 pack64(float d, int j) {
    // d >= 0 -> f32 bits order-preserving; u64 ascending == lex (d, j)
    return ((u64)__float_as_uint(d) << 32) | (unsigned)j;
}

__device__ __forceinline__ unsigned bf16rn(float x) {
    unsigned u = __float_as_uint(x);
    return (u + 0x7fffu + ((u >> 16) & 1u)) >> 16;
}

// ---------------------------------------------------------------------------
// Kernel 1: prep. sq (exact ascending-k fmaf chain — recheck uses the same
// chain so dot(i,i)==sq[i] bit-exact => d(i,i)==0), transposed bf16 hi/lo
// split (MFMA fragments = contiguous 16B), transposed fp32 Xt32 for recheck.
// ---------------------------------------------------------------------------
__global__ __launch_bounds__(256) void prep_kernel(const float* __restrict__ crd,
                                                   float* __restrict__ sq,
                                                   ushort_t* __restrict__ XtHi,
                                                   ushort_t* __restrict__ XtLo,
                                                   float* __restrict__ Xt32) {
    const int f = blockIdx.x * 256 + threadIdx.x;
    float acc = 0.f;
#pragma unroll
    for (int kb = 0; kb < 8; ++kb) {
        ushort_t hb[8], lb[8];
        float    xv[8];
#pragma unroll
        for (int u = 0; u < 8; ++u) {
            int k = kb * 8 + u;
            float x = crd[k * F + f];
            acc = fmaf(x, x, acc);
            unsigned h = bf16rn(x);
            float hf = __uint_as_float(h << 16);
            unsigned l = bf16rn(x - hf);       // Dekker split, exact residual
            hb[u] = (ushort_t)h; lb[u] = (ushort_t)l; xv[u] = x;
        }
        *(uint4*)&XtHi[(size_t)f * KD + kb * 8] = *(const uint4*)hb;
        *(uint4*)&XtLo[(size_t)f * KD + kb * 8] = *(const uint4*)lb;
        *(float4*)&Xt32[(size_t)f * KD + kb * 8]     = *(const float4*)&xv[0];
        *(float4*)&Xt32[(size_t)f * KD + kb * 8 + 4] = *(const float4*)&xv[4];
    }
    sq[f] = acc;
}

// ---------------------------------------------------------------------------
// Kernel 2: MFMA distance + approx top-16 per (row, col-quarter).
// R8 post-mortem: the serial fold (1 thread/row, dependent ds_read_b64 per
// entry ~120cyc x 128 entries x 5 folds ~ 60k cyc/block) dominated — both
// pipes idle at the fold barriers. Fixes: (1) batched 8-wide fold loads
// (one LDS latency per 8 entries); (2) 64-col rounds, folds at 0,1,3,7,15,31
// with round 0 = 64 fixed slots; (3) 256-thr blocks, 32 rows x 2048 cols,
// grid 1024 = 4 blocks/CU (16 waves/CU), __launch_bounds__(256,4).
// Structure: 4 waves share 32 rows (A frags resident), distinct 16-col
// stripes; 12 MFMAs/wave-round; unroll-2 double-buffered B prefetch; accept
// test dot >= pre[r] + 0.5*sqj (superset of exact d<=thr, MARGIN-covered).
// ---------------------------------------------------------------------------
__global__ __launch_bounds__(256, 4) void knn_mfma(const ushort_t* __restrict__ XtHi,
                                                   const ushort_t* __restrict__ XtLo,
                                                   const float* __restrict__ sq,
                                                   u64* __restrict__ part) {
    __shared__ u64 buf[WROWS][CAP + 1];     // 24.8 KB
    __shared__ u64 lst[WROWS][MKEEP + 1];   // 4.4 KB
    __shared__ __align__(16) float thr[WROWS];
    __shared__ int cnt[WROWS];

    const int tid  = threadIdx.x;
    const int wave = tid >> 6;
    const int tx   = tid & 63;
    const int quad = tx >> 4;
    const int n    = tx & 15;
    const int blockRow = (blockIdx.x >> 2) * WROWS;
    const int jq    = blockIdx.x & 3;
    const int jbase = jq * (F / JQ);

    if (tid < WROWS) { cnt[tid] = 0; thr[tid] = __int_as_float(0x7f800000); }
#pragma unroll
    for (int e = tid; e < WROWS * MKEEP; e += 256) lst[e >> 4][e & 15] = ~0ULL;
    __syncthreads();

    // A fragments for both 16-row tiles, resident all sweep
    const size_t a0 = (size_t)(blockRow + n) * KD + quad * 8;
    const size_t a1 = (size_t)(blockRow + 16 + n) * KD + quad * 8;
    const bf16x8 a0h0 = *(const bf16x8*)(XtHi + a0), a0h1 = *(const bf16x8*)(XtHi + a0 + 32);
    const bf16x8 a0l0 = *(const bf16x8*)(XtLo + a0), a0l1 = *(const bf16x8*)(XtLo + a0 + 32);
    const bf16x8 a1h0 = *(const bf16x8*)(XtHi + a1), a1h1 = *(const bf16x8*)(XtHi + a1 + 32);
    const bf16x8 a1l0 = *(const bf16x8*)(XtLo + a1), a1l1 = *(const bf16x8*)(XtLo + a1 + 32);
    const f32x4 sqi0 = *(const f32x4*)&sq[blockRow + quad * 4];
    const f32x4 sqi1 = *(const f32x4*)&sq[blockRow + 16 + quad * 4];
    f32x4 pre0, pre1;   // 0.5*(sqi - thr); -inf => accept-all
#pragma unroll
    for (int r = 0; r < 4; ++r) { pre0[r] = -__int_as_float(0x7f800000);
                                  pre1[r] = -__int_as_float(0x7f800000); }

    const int laneCol = wave * 16 + n;    // col offset within a round's 64

#define LOADB(H0, H1, L0, L1, SJ, RND)                                        \
    {   int jc = jbase + (RND) * CPR + laneCol;                               \
        size_t bo = (size_t)jc * KD + quad * 8;                               \
        H0 = *(const bf16x8*)(XtHi + bo); H1 = *(const bf16x8*)(XtHi + bo + 32); \
        L0 = *(const bf16x8*)(XtLo + bo); L1 = *(const bf16x8*)(XtLo + bo + 32); \
        SJ = sq[jc]; }

#define MFMABODY(H0, H1, L0, L1)                                              \
        f32x4 za0 = {0,0,0,0}, zb0 = {0,0,0,0}, za1 = {0,0,0,0}, zb1 = {0,0,0,0}; \
        za0 = __builtin_amdgcn_mfma_f32_16x16x32_bf16(a0h0, H0, za0, 0, 0, 0); \
        za0 = __builtin_amdgcn_mfma_f32_16x16x32_bf16(a0h1, H1, za0, 0, 0, 0); \
        zb0 = __builtin_amdgcn_mfma_f32_16x16x32_bf16(a0h0, L0, zb0, 0, 0, 0); \
        zb0 = __builtin_amdgcn_mfma_f32_16x16x32_bf16(a0h1, L1, zb0, 0, 0, 0); \
        zb0 = __builtin_amdgcn_mfma_f32_16x16x32_bf16(a0l0, H0, zb0, 0, 0, 0); \
        zb0 = __builtin_amdgcn_mfma_f32_16x16x32_bf16(a0l1, H1, zb0, 0, 0, 0); \
        za1 = __builtin_amdgcn_mfma_f32_16x16x32_bf16(a1h0, H0, za1, 0, 0, 0); \
        za1 = __builtin_amdgcn_mfma_f32_16x16x32_bf16(a1h1, H1, za1, 0, 0, 0); \
        zb1 = __builtin_amdgcn_mfma_f32_16x16x32_bf16(a1h0, L0, zb1, 0, 0, 0); \
        zb1 = __builtin_amdgcn_mfma_f32_16x16x32_bf16(a1h1, L1, zb1, 0, 0, 0); \
        zb1 = __builtin_amdgcn_mfma_f32_16x16x32_bf16(a1l0, H0, zb1, 0, 0, 0); \
        zb1 = __builtin_amdgcn_mfma_f32_16x16x32_bf16(a1l1, H1, zb1, 0, 0, 0);

// round 0: accept-all, deterministic slot = laneCol (no atomics)
#define PROCESS0(H0, H1, L0, L1, SJ, RND)                                     \
    {   MFMABODY(H0, H1, L0, L1)                                              \
        const int jc = jbase + (RND) * CPR + laneCol;                         \
        _Pragma("unroll")                                                     \
        for (int r = 0; r < 4; ++r) {                                         \
            float d0 = fmaxf((sqi0[r] + SJ) - 2.f * (za0[r] + zb0[r]), 0.f);  \
            buf[quad * 4 + r][laneCol] = pack64(d0, jc);                      \
            float d1 = fmaxf((sqi1[r] + SJ) - 2.f * (za1[r] + zb1[r]), 0.f);  \
            buf[16 + quad * 4 + r][laneCol] = pack64(d1, jc);                 \
        } }

#define PROCESS(H0, H1, L0, L1, SJ, RND)                                      \
    {   MFMABODY(H0, H1, L0, L1)                                              \
        const int jc = jbase + (RND) * CPR + laneCol;                         \
        const float h = 0.5f * SJ;                                            \
        _Pragma("unroll")                                                     \
        for (int r = 0; r < 4; ++r) {                                         \
            float dot = za0[r] + zb0[r];                                      \
            if (dot >= pre0[r] + h) {                                         \
                float d = fmaxf((sqi0[r] + SJ) - 2.f * dot, 0.f);             \
                int row = quad * 4 + r;                                       \
                int q = atomicAdd(&cnt[row], 1);                              \
                if (q < CAP) buf[row][q] = pack64(d, jc);                     \
            }                                                                 \
            dot = za1[r] + zb1[r];                                            \
            if (dot >= pre1[r] + h) {                                         \
                float d = fmaxf((sqi1[r] + SJ) - 2.f * dot, 0.f);             \
                int row = 16 + quad * 4 + r;                                  \
                int q = atomicAdd(&cnt[row], 1);                              \
                if (q < CAP) buf[row][q] = pack64(d, jc);                     \
            }                                                                 \
        } }

// batched fold: 8 independent LDS loads per group -> one latency per 8
#define FOLD(NN)                                                              \
    {   __syncthreads();                                                      \
        if (tid < WROWS) {                                                    \
            u64 L[MKEEP];                                                     \
            _Pragma("unroll")                                                 \
            for (int s = 0; s < MKEEP; ++s) L[s] = lst[tid][s];               \
            int nn = min((NN), CAP);                                          \
            for (int ii = 0; ii < nn; ii += 8) {                              \
                u64 batch[8];                                                 \
                _Pragma("unroll")                                             \
                for (int b = 0; b < 8; ++b)                                   \
                    batch[b] = (ii + b < nn) ? buf[tid][ii + b] : ~0ULL;      \
                _Pragma("unroll")                                             \
                for (int b = 0; b < 8; ++b) {                                 \
                    u64 x = batch[b];                                         \
                    if (x < L[MKEEP - 1]) {                                   \
                        L[MKEEP - 1] = x;                                     \
                        _Pragma("unroll")                                     \
                        for (int q = MKEEP - 1; q > 0; --q)                   \
                            if (L[q] < L[q - 1]) { u64 w = L[q]; L[q] = L[q - 1]; L[q - 1] = w; } \
                    }                                                         \
                }                                                             \
            }                                                                 \
            _Pragma("unroll")                                                 \
            for (int s = 0; s < MKEEP; ++s) lst[tid][s] = L[s];               \
            thr[tid] = __uint_as_float((unsigned)(L[NB - 1] >> 32)) + MARGIN; \
            cnt[tid] = 0;                                                     \
        }                                                                     \
        __syncthreads();                                                      \
        {   f32x4 t0 = *(const f32x4*)&thr[quad * 4];                         \
            f32x4 t1 = *(const f32x4*)&thr[16 + quad * 4];                    \
            _Pragma("unroll")                                                 \
            for (int r = 0; r < 4; ++r) {                                     \
                pre0[r] = 0.5f * (sqi0[r] - t0[r]);                           \
                pre1[r] = 0.5f * (sqi1[r] - t1[r]);                           \
            } } }

    bf16x8 B0h0, B0h1, B0l0, B0l1, B1h0, B1h1, B1l0, B1l1;
    float  B0sj, B1sj;
    LOADB(B0h0, B0h1, B0l0, B0l1, B0sj, 0)
    LOADB(B1h0, B1h1, B1l0, B1l1, B1sj, 1)

    PROCESS0(B0h0, B0h1, B0l0, B0l1, B0sj, 0)
    LOADB(B0h0, B0h1, B0l0, B0l1, B0sj, 2)
    FOLD(64)
    PROCESS(B1h0, B1h1, B1l0, B1l1, B1sj, 1)
    LOADB(B1h0, B1h1, B1l0, B1l1, B1sj, 3)
    FOLD(cnt[tid])

    for (int rr = 2; rr < NROUND; rr += 2) {
        PROCESS(B0h0, B0h1, B0l0, B0l1, B0sj, rr)
        if (rr + 2 < NROUND) LOADB(B0h0, B0h1, B0l0, B0l1, B0sj, rr + 2)
        PROCESS(B1h0, B1h1, B1l0, B1l1, B1sj, rr + 1)
        if (rr + 3 < NROUND) LOADB(B1h0, B1h1, B1l0, B1l1, B1sj, rr + 3)
        if (((rr + 1) & (rr + 2)) == 0) FOLD(cnt[tid])   // rounds 3,7,15,31
    }

    // write per-quarter top-16 lists (final fold happened at round 31)
#pragma unroll
    for (int e = tid; e < WROWS * MKEEP; e += 256) {
        int rrw = e >> 4, ss = e & 15;
        part[((size_t)jq * F + blockRow + rrw) * MKEEP + ss] = lst[rrw][ss];
    }
#undef LOADB
#undef MFMABODY
#undef PROCESS0
#undef PROCESS
#undef FOLD
}

// ---------------------------------------------------------------------------
// Kernel 3: exact recheck. Block = 4 rows x 64 candidates (one row per wave).
// B rows contiguous from Xt32 (256B/candidate, L2-hot); A row in LDS.
// Exact ascending-k fmaf chain (bit-identical to sq's => d(i,i)==0).
// Top-8 via in-register wave shuffle-pop on packed u64 -> exact jax tie-break.
// ---------------------------------------------------------------------------
__global__ __launch_bounds__(256) void recheck_kernel(const float* __restrict__ Xt32,
                                                      const float* __restrict__ sq,
                                                      const u64* __restrict__ part,
                                                      int* __restrict__ knn) {
    __shared__ float A_s[4][KD];
    const int tid = threadIdx.x;
    const int rl = tid >> 6, tx = tid & 63;
    const int i = blockIdx.x * 4 + rl;

    A_s[tid >> 6][tid & 63] = Xt32[(size_t)(blockIdx.x * 4 + (tid >> 6)) * KD + (tid & 63)];
    __syncthreads();

    u64 pc = part[((size_t)(tx >> 4) * F + i) * MKEEP + (tx & 15)];
    int j = (int)(pc & 0xffffffffu);

    const float4* b4 = (const float4*)(Xt32 + (size_t)j * KD);
    float acc = 0.f;
#pragma unroll
    for (int kk = 0; kk < KD / 4; ++kk) {
        float4 b = b4[kk];
        const float* a = &A_s[rl][kk * 4];
        acc = fmaf(a[0], b.x, acc);
        acc = fmaf(a[1], b.y, acc);
        acc = fmaf(a[2], b.z, acc);
        acc = fmaf(a[3], b.w, acc);
    }
    float d = fmaxf((sq[i] + sq[j]) - 2.f * acc, 0.f);
    u64 mine = pack64(d, j);

    int myout = 0;
#pragma unroll
    for (int s = 0; s < NB; ++s) {
        u64 m = mine;
#pragma unroll
        for (int off = 32; off >= 1; off >>= 1) {
            u64 o = __shfl_xor(m, off, 64);
            if (o < m) m = o;
        }
        if (mine == m) mine = ~0ULL;       // pop (unique (d,j) per row)
        if (tx == s) myout = (int)(m & 0xffffffffu);
    }
    if (tx < NB) knn[(size_t)i * NB + tx] = myout;
}

// ---------------------------------------------------------------------------
// Kernel 4: gather. 4 blocks per (b,c); row staged in LDS; int4 knn +
// float4 stores, coalesced.
// ---------------------------------------------------------------------------
__global__ __launch_bounds__(512) void gather_kernel(const float* __restrict__ inp,
                                                     const int* __restrict__ knn,
                                                     float* __restrict__ out) {
    __shared__ float row[F];    // 32 KB
    const int bc    = blockIdx.x >> 2;
    const int chunk = blockIdx.x & 3;
    const int tid   = threadIdx.x;

    const float4* in4  = (const float4*)(inp + (size_t)bc * F);
    float4*       row4 = (float4*)row;
#pragma unroll
    for (int i = 0; i < (F / 4) / 512; ++i) row4[i * 512 + tid] = in4[i * 512 + tid];
    __syncthreads();

    const int4* kn4 = (const int4*)knn;
    float4*     ou4 = (float4*)(out + (size_t)bc * (F * NB));

#pragma unroll
    for (int i = 0; i < 8; ++i) {
        int e = chunk * 4096 + i * 512 + tid;
        int4 idx = kn4[e];
        if (e == 0) idx.x = 0;             // flat_idx[0] hardcoded 0
        float4 o;
        o.x = row[idx.x]; o.y = row[idx.y]; o.z = row[idx.z]; o.w = row[idx.w];
        ou4[e] = o;
    }
}

extern "C" void kernel_launch(void* const* d_in, const int* in_sizes, int n_in,
                              void* d_out, int out_size, void* d_ws, size_t ws_size,
                              hipStream_t stream) {
    const float* inp = (const float*)d_in[0];   // (64,4,8192,1) fp32
    const float* crd = (const float*)d_in[1];   // (64,1,8192)  fp32
    float* out = (float*)d_out;                 // (64,4,65536,1) fp32

    ushort_t* XtHi = (ushort_t*)d_ws;                               // 1 MB
    ushort_t* XtLo = (ushort_t*)((char*)d_ws + (1u << 20));         // 1 MB
    float*    Xt32 = (float*)((char*)d_ws + (2u << 20));            // 2 MB
    float*    sq   = (float*)((char*)d_ws + (4u << 20));            // 32 KB
    int*      knn  = (int*)((char*)d_ws + (4u << 20) + (1u << 15)); // 256 KB
    u64*      part = (u64*)((char*)d_ws + (5u << 20));              // 4 MB

    prep_kernel<<<F / 256, 256, 0, stream>>>(crd, sq, XtHi, XtLo, Xt32);
    knn_mfma<<<(F / WROWS) * JQ, 256, 0, stream>>>(XtHi, XtLo, sq, part);
    recheck_kernel<<<F / 4, 256, 0, stream>>>(Xt32, sq, part, knn);
    gather_kernel<<<256 * 4, 512, 0, stream>>>(inp, knn, out);
}